// Round 1
// baseline (1350.922 us; speedup 1.0000x reference)
//
#include <hip/hip_runtime.h>
#include <hip/hip_bf16.h>
#include <cstddef>

#define F_    65536
#define LP_   8
#define NL_   8192
#define DG_   64
#define D_    32
#define ITERS_ 8

// ---------------- helpers ----------------
__device__ __forceinline__ float sigmoidf_(float x) { return 1.0f / (1.0f + __expf(-x)); }
__device__ __forceinline__ float tanhf_(float x)    { return 1.0f - 2.0f / (__expf(2.0f * x) + 1.0f); }
__device__ __forceinline__ float seluf_(float x) {
    const float a = 1.6732632423543772f, s = 1.0507009873554805f;
    return x > 0.0f ? s * x : s * a * (__expf(x) - 1.0f);
}
__device__ __forceinline__ float softplusf_(float x) { return x > 20.0f ? x : log1pf(__expf(x)); }

#define REP32(M) M(0)M(1)M(2)M(3)M(4)M(5)M(6)M(7)M(8)M(9)M(10)M(11)M(12)M(13)M(14)M(15) \
                 M(16)M(17)M(18)M(19)M(20)M(21)M(22)M(23)M(24)M(25)M(26)M(27)M(28)M(29)M(30)M(31)

// broadcast lane i's value within each 32-lane group (1 instr, no addr reg)
#define BC32(src, i) __int_as_float(__builtin_amdgcn_ds_swizzle(__float_as_int(src), ((i) << 5)))

// ---------------- one-time weight transposes into ws ----------------
__global__ __launch_bounds__(256) void k_transpose(
    const float* __restrict__ lg_w, const float* __restrict__ lg_u,
    const float* __restrict__ att_w, const float* __restrict__ ro_w1, const float* __restrict__ ro_w2,
    float* __restrict__ lg_wT, float* __restrict__ lg_uT, float* __restrict__ att_wT,
    float* __restrict__ ro_w1T, float* __restrict__ ro_w2T)
{
    int tid = blockIdx.x * blockDim.x + threadIdx.x;
    int stride = gridDim.x * blockDim.x;
    for (int e = tid; e < 3072; e += stride) { int k = e >> 5, i = e & 31; lg_wT[e] = lg_w[i * 96 + k]; }
    for (int e = tid; e < 3072; e += stride) { int k = e >> 5, i = e & 31; lg_uT[e] = lg_u[i * 96 + k]; }
    for (int e = tid; e < 1024; e += stride) { int j = e >> 5, i = e & 31; att_wT[e] = att_w[i * 32 + j]; }
    for (int e = tid; e < 512;  e += stride) { int j = e >> 5, i = e & 31; ro_w1T[e] = ro_w1[i * 16 + j]; }
    for (int e = tid; e < 128;  e += stride) { int j = e >> 4, i = e & 15; ro_w2T[e] = ro_w2[i * 8 + j]; }
}

// ---------------- init: path_state -> pss[:,8,:] ----------------
__global__ __launch_bounds__(256) void k_init_path(
    const float* __restrict__ tr, const float* __restrict__ len,
    const float* __restrict__ loss, const float* __restrict__ prop,
    const float* __restrict__ fe_w1, const float* __restrict__ fe_b1,
    const float* __restrict__ fe_w2, const float* __restrict__ fe_b2,
    float* __restrict__ pss)
{
    const int j = threadIdx.x & 31;
    const int half = (threadIdx.x >> 5) & 1;
    float w2c[32];
#pragma unroll
    for (int i = 0; i < 32; i++) w2c[i] = fe_w2[i * 32 + j];
    const float w10 = fe_w1[j], w11 = fe_w1[32 + j], w12 = fe_w1[64 + j], w13 = fe_w1[96 + j];
    const float b1 = fe_b1[j], b2 = fe_b2[j];
    const int wave = (blockIdx.x * blockDim.x + threadIdx.x) >> 6;
    const int nw = (gridDim.x * blockDim.x) >> 6;
    for (int fp = wave; fp < F_ / 2; fp += nw) {
        const int f = fp * 2 + half;
        float p0 = (tr[f]   - 0.5f) * 2.0f;
        float p1 = (len[f]  - 0.5f) * 2.0f;
        float p2 = (loss[f] - 0.1f) * 5.0f;
        float p3 = (prop[f] - 0.2f) * 3.0f;
        float h1 = seluf_(fmaf(p0, w10, fmaf(p1, w11, fmaf(p2, w12, fmaf(p3, w13, b1)))));
        float acc = b2;
#define ISTEP(i) { float hv = BC32(h1, i); acc = fmaf(hv, w2c[i], acc); }
        REP32(ISTEP)
#undef ISTEP
        pss[(size_t)f * 288 + 8 * 32 + j] = seluf_(acc);
    }
}

// ---------------- init: link load + link_state ----------------
__global__ __launch_bounds__(256) void k_init_link(
    const float* __restrict__ tr, const float* __restrict__ cap, const int* __restrict__ f2lf,
    const float* __restrict__ le_w1, const float* __restrict__ le_b1,
    const float* __restrict__ le_w2, const float* __restrict__ le_b2,
    float* __restrict__ link_state)
{
    const int lane = threadIdx.x & 63;
    const int j = lane & 31;
    float w2c[32];
#pragma unroll
    for (int i = 0; i < 32; i++) w2c[i] = le_w2[i * 32 + j];
    const float w10 = le_w1[j], w11 = le_w1[32 + j];
    const float b1 = le_b1[j], b2 = le_b2[j];
    const int wave = (blockIdx.x * blockDim.x + threadIdx.x) >> 6;
    const int nw = (gridDim.x * blockDim.x) >> 6;
    for (int l = wave; l < NL_; l += nw) {
        int fidx = f2lf[l * 64 + lane];
        float s = tr[fidx];
        s += __shfl_xor(s, 1);  s += __shfl_xor(s, 2);  s += __shfl_xor(s, 4);
        s += __shfl_xor(s, 8);  s += __shfl_xor(s, 16); s += __shfl_xor(s, 32);
        float c = cap[l];
        float load = s * (1.0f / 64.0f) / c;
        float lf0 = (c - 1.0f);
        float h1 = seluf_(fmaf(lf0, w10, fmaf(load, w11, b1)));
        float acc = b2;
#define LSTEP(i) { float hv = BC32(h1, i); acc = fmaf(hv, w2c[i], acc); }
        REP32(LSTEP)
#undef LSTEP
        if (lane < 32) link_state[l * 32 + j] = seluf_(acc);
    }
}

// ---------------- per-iter: mx_link = link_state @ pg_w + pg_b[0] ----------------
__global__ __launch_bounds__(256) void k_mx_link(
    const float* __restrict__ link_state, const float* __restrict__ pg_w,
    const float* __restrict__ pg_b, float* __restrict__ mx_link)
{
    const int j = threadIdx.x & 31;
    const int half = (threadIdx.x >> 5) & 1;
    float wz[32], wr[32], wh[32];
#pragma unroll
    for (int i = 0; i < 32; i++) {
        wz[i] = pg_w[i * 96 + j];
        wr[i] = pg_w[i * 96 + 32 + j];
        wh[i] = pg_w[i * 96 + 64 + j];
    }
    const float b0z = pg_b[j], b0r = pg_b[32 + j], b0h = pg_b[64 + j];
    const int wave = (blockIdx.x * blockDim.x + threadIdx.x) >> 6;
    const int nw = (gridDim.x * blockDim.x) >> 6;
    for (int lp = wave; lp < NL_ / 2; lp += nw) {
        const int l = lp * 2 + half;
        float ls = link_state[l * 32 + j];
        float az = b0z, ar = b0r, ah = b0h;
#define MSTEP(i) { float lv = BC32(ls, i); az = fmaf(lv, wz[i], az); ar = fmaf(lv, wr[i], ar); ah = fmaf(lv, wh[i], ah); }
        REP32(MSTEP)
#undef MSTEP
        float* mp = mx_link + l * 96;
        mp[j] = az; mp[32 + j] = ar; mp[64 + j] = ah;
    }
}

// ---------------- per-iter: path GRU over LP steps, writes pss[:,0..8,:] ----------------
__global__ __launch_bounds__(256) void k_path(
    const float* __restrict__ mx_link, const float* __restrict__ pg_u,
    const float* __restrict__ pg_b, const int* __restrict__ l2f,
    float* __restrict__ pss)
{
    const int j = threadIdx.x & 31;
    const int half = (threadIdx.x >> 5) & 1;
    float uz[32], ur[32], uh[32];
#pragma unroll
    for (int i = 0; i < 32; i++) {
        uz[i] = pg_u[i * 96 + j];
        ur[i] = pg_u[i * 96 + 32 + j];
        uh[i] = pg_u[i * 96 + 64 + j];
    }
    const float b1z = pg_b[96 + j], b1r = pg_b[96 + 32 + j], b1h = pg_b[96 + 64 + j];
    const int wave = (blockIdx.x * blockDim.x + threadIdx.x) >> 6;
    const int nw = (gridDim.x * blockDim.x) >> 6;
    for (int fp = wave; fp < F_ / 2; fp += nw) {
        const int f = fp * 2 + half;
        float* prow = pss + (size_t)f * 288;
        const int* lrow = l2f + f * 8;
        int lk[8];
#pragma unroll
        for (int t = 0; t < 8; t++) lk[t] = lrow[t];
        float hc = prow[8 * 32 + j];
        prow[j] = hc;  // pss[f][0] = prev
#pragma unroll
        for (int t = 0; t < 8; t++) {
            const float* mxp = mx_link + lk[t] * 96;
            float mxz = mxp[j], mxr = mxp[32 + j], mxh = mxp[64 + j];
            float az = b1z, ar = b1r, ah = b1h;
#define GSTEP(i) { float hv = BC32(hc, i); az = fmaf(hv, uz[i], az); ar = fmaf(hv, ur[i], ar); ah = fmaf(hv, uh[i], ah); }
            REP32(GSTEP)
#undef GSTEP
            float z = sigmoidf_(mxz + az);
            float r = sigmoidf_(mxr + ar);
            float c = tanhf_(mxh + r * ah);
            hc = fmaf(z, hc, (1.0f - z) * c);
            prow[(t + 1) * 32 + j] = hc;
        }
    }
}

// ---------------- per-iter: attention + aggregate -> agg[NL,32] ----------------
__global__ __launch_bounds__(256) void k_att(
    const float* __restrict__ pss, const int* __restrict__ f2lf, const int* __restrict__ f2lp,
    const float* __restrict__ att_wT, const float* __restrict__ att_b,
    float* __restrict__ agg)
{
    __shared__ float red[4][64][33];
    const int w = threadIdx.x >> 6;
    const int lane = threadIdx.x & 63;
    const int l = blockIdx.x * 4 + w;  // one link per wave, grid exactly covers NL
    const int fi = f2lf[l * 64 + lane];
    const int pi = f2lp[l * 64 + lane];
    const float* row = pss + ((size_t)fi * 9 + pi) * 32;
    float pg[32];
#pragma unroll
    for (int i = 0; i < 8; i++) {
        float4 v = ((const float4*)row)[i];
        pg[4 * i] = v.x; pg[4 * i + 1] = v.y; pg[4 * i + 2] = v.z; pg[4 * i + 3] = v.w;
    }
    float a[32];
#pragma unroll
    for (int jj = 0; jj < 32; jj++) {
        float acc = att_b[jj];
#pragma unroll
        for (int i = 0; i < 32; i++) acc = fmaf(pg[i], att_wT[jj * 32 + i], acc);
        a[jj] = acc > 0.0f ? acc : 0.2f * acc;   // leaky_relu 0.2
    }
    float m = a[0];
#pragma unroll
    for (int jj = 1; jj < 32; jj++) m = fmaxf(m, a[jj]);
    float ssum = 0.0f;
#pragma unroll
    for (int jj = 0; jj < 32; jj++) { a[jj] = __expf(a[jj] - m); ssum += a[jj]; }
    float inv = 1.0f / ssum;
    float* myrow = &red[w][lane][0];
#pragma unroll
    for (int jj = 0; jj < 32; jj++) myrow[jj] = a[jj] * inv * pg[jj];
    __syncthreads();
    const int j = lane & 31, hh = lane >> 5;
    float s = 0.0f;
#pragma unroll
    for (int d = 0; d < 32; d++) s += red[w][hh * 32 + d][j];
    s += __shfl_xor(s, 32);
    if (lane < 32) agg[l * 32 + j] = s;
}

// ---------------- per-iter: link GRU (in-place, barrier-protected) ----------------
__global__ __launch_bounds__(256) void k_link_gru(
    const float* __restrict__ agg, const float* __restrict__ lg_wT,
    const float* __restrict__ lg_uT, const float* __restrict__ lg_b,
    float* __restrict__ link_state)
{
    const int lane = threadIdx.x & 63;
    const int w = threadIdx.x >> 6;      // j-part: wave w handles gate dims [8w, 8w+8)
    const int l = blockIdx.x * 64 + lane;
    const float* hrow = link_state + l * 32;
    const float* xrow = agg + l * 32;
    float h[32], x[32];
#pragma unroll
    for (int i = 0; i < 8; i++) {
        float4 v = ((const float4*)hrow)[i];
        h[4 * i] = v.x; h[4 * i + 1] = v.y; h[4 * i + 2] = v.z; h[4 * i + 3] = v.w;
        float4 u = ((const float4*)xrow)[i];
        x[4 * i] = u.x; x[4 * i + 1] = u.y; x[4 * i + 2] = u.z; x[4 * i + 3] = u.w;
    }
    float hj[8];
#pragma unroll
    for (int jo = 0; jo < 8; jo++) hj[jo] = hrow[w * 8 + jo];
    __syncthreads();   // all loads of old link_state complete before any wave stores
#pragma unroll
    for (int jo = 0; jo < 8; jo++) {
        const int j = w * 8 + jo;
        float mz = lg_b[j], mr = lg_b[32 + j], mh = lg_b[64 + j];
        float hz = lg_b[96 + j], hr = lg_b[96 + 32 + j], hhs = lg_b[96 + 64 + j];
        const float* wtz = lg_wT + j * 32;
        const float* wtr = lg_wT + (32 + j) * 32;
        const float* wth = lg_wT + (64 + j) * 32;
        const float* utz = lg_uT + j * 32;
        const float* utr = lg_uT + (32 + j) * 32;
        const float* uth = lg_uT + (64 + j) * 32;
#pragma unroll
        for (int i = 0; i < 32; i++) {
            mz  = fmaf(x[i], wtz[i], mz);
            mr  = fmaf(x[i], wtr[i], mr);
            mh  = fmaf(x[i], wth[i], mh);
            hz  = fmaf(h[i], utz[i], hz);
            hr  = fmaf(h[i], utr[i], hr);
            hhs = fmaf(h[i], uth[i], hhs);
        }
        float z = sigmoidf_(mz + hz);
        float r = sigmoidf_(mr + hr);
        float c = tanhf_(mh + r * hhs);
        link_state[l * 32 + j] = fmaf(z, hj[jo], (1.0f - z) * c);
    }
}

// ---------------- readout ----------------
__global__ __launch_bounds__(256) void k_readout(
    const float* __restrict__ pss, const int* __restrict__ l2f,
    const float* __restrict__ cap, const float* __restrict__ prop,
    const float* __restrict__ w1T, const float* __restrict__ b1,
    const float* __restrict__ w2T, const float* __restrict__ b2,
    const float* __restrict__ w3, const float* __restrict__ b3,
    float* __restrict__ out)
{
    const int tid = blockIdx.x * blockDim.x + threadIdx.x;  // F*8 total
    const int f = tid >> 3, t = tid & 7;
    const float* row = pss + ((size_t)f * 9 + 1 + t) * 32;
    float xr[32];
#pragma unroll
    for (int i = 0; i < 8; i++) {
        float4 v = ((const float4*)row)[i];
        xr[4 * i] = v.x; xr[4 * i + 1] = v.y; xr[4 * i + 2] = v.z; xr[4 * i + 3] = v.w;
    }
    float h1[16];
#pragma unroll
    for (int j = 0; j < 16; j++) {
        float acc = b1[j];
#pragma unroll
        for (int i = 0; i < 32; i++) acc = fmaf(xr[i], w1T[j * 32 + i], acc);
        h1[j] = seluf_(acc);
    }
    float h2[8];
#pragma unroll
    for (int j = 0; j < 8; j++) {
        float acc = b2[j];
#pragma unroll
        for (int i = 0; i < 16; i++) acc = fmaf(h1[i], w2T[j * 16 + i], acc);
        h2[j] = seluf_(acc);
    }
    float o = b3[0];
#pragma unroll
    for (int i = 0; i < 8; i++) o = fmaf(h2[i], w3[i], o);
    o = softplusf_(o);
    int link = l2f[f * 8 + t];
    float v = o / cap[link];
    v += __shfl_xor(v, 1, 8);
    v += __shfl_xor(v, 2, 8);
    v += __shfl_xor(v, 4, 8);
    if (t == 0) out[f] = v + prop[f];
}

// ---------------- host ----------------
extern "C" void kernel_launch(void* const* d_in, const int* in_sizes, int n_in,
                              void* d_out, int out_size, void* d_ws, size_t ws_size,
                              hipStream_t stream) {
    const float* flow_traffic = (const float*)d_in[0];
    const float* flow_length  = (const float*)d_in[1];
    const float* flow_loss    = (const float*)d_in[2];
    const float* flow_prop    = (const float*)d_in[3];
    const float* link_cap     = (const float*)d_in[5];
    const int*   l2f          = (const int*)d_in[6];
    const int*   f2lf         = (const int*)d_in[7];
    const int*   f2lp         = (const int*)d_in[8];
    const float* fe_w1 = (const float*)d_in[9],  *fe_b1 = (const float*)d_in[10];
    const float* fe_w2 = (const float*)d_in[11], *fe_b2 = (const float*)d_in[12];
    const float* le_w1 = (const float*)d_in[13], *le_b1 = (const float*)d_in[14];
    const float* le_w2 = (const float*)d_in[15], *le_b2 = (const float*)d_in[16];
    const float* att_w = (const float*)d_in[17], *att_b = (const float*)d_in[18];
    const float* pg_w  = (const float*)d_in[19], *pg_u  = (const float*)d_in[20], *pg_b = (const float*)d_in[21];
    const float* lg_w  = (const float*)d_in[22], *lg_u  = (const float*)d_in[23], *lg_b = (const float*)d_in[24];
    const float* ro_w1 = (const float*)d_in[25], *ro_b1 = (const float*)d_in[26];
    const float* ro_w2 = (const float*)d_in[27], *ro_b2 = (const float*)d_in[28];
    const float* ro_w3 = (const float*)d_in[29], *ro_b3 = (const float*)d_in[30];
    float* out = (float*)d_out;

    float* ws = (float*)d_ws;
    float* pss        = ws;                                   // F*9*32
    float* link_state = pss + (size_t)F_ * 288;               // NL*32
    float* mx_link    = link_state + NL_ * 32;                // NL*96
    float* agg        = mx_link + NL_ * 96;                   // NL*32
    float* lg_wT      = agg + NL_ * 32;                       // 3072
    float* lg_uT      = lg_wT + 3072;                         // 3072
    float* att_wT     = lg_uT + 3072;                         // 1024
    float* ro_w1T     = att_wT + 1024;                        // 512
    float* ro_w2T     = ro_w1T + 512;                         // 128

    k_transpose<<<8, 256, 0, stream>>>(lg_w, lg_u, att_w, ro_w1, ro_w2,
                                       lg_wT, lg_uT, att_wT, ro_w1T, ro_w2T);
    k_init_path<<<512, 256, 0, stream>>>(flow_traffic, flow_length, flow_loss, flow_prop,
                                         fe_w1, fe_b1, fe_w2, fe_b2, pss);
    k_init_link<<<512, 256, 0, stream>>>(flow_traffic, link_cap, f2lf,
                                         le_w1, le_b1, le_w2, le_b2, link_state);
    for (int it = 0; it < ITERS_; ++it) {
        k_mx_link<<<64, 256, 0, stream>>>(link_state, pg_w, pg_b, mx_link);
        k_path<<<1024, 256, 0, stream>>>(mx_link, pg_u, pg_b, l2f, pss);
        k_att<<<NL_ / 4, 256, 0, stream>>>(pss, f2lf, f2lp, att_wT, att_b, agg);
        k_link_gru<<<NL_ / 64, 256, 0, stream>>>(agg, lg_wT, lg_uT, lg_b, link_state);
    }
    k_readout<<<F_ * 8 / 256, 256, 0, stream>>>(pss, l2f, link_cap, flow_prop,
                                                ro_w1T, ro_b1, ro_w2T, ro_b2, ro_w3, ro_b3, out);
}

// Round 3
// 1083.718 us; speedup vs baseline: 1.2466x; 1.2466x over previous
//
#include <hip/hip_runtime.h>
#include <hip/hip_bf16.h>
#include <cstddef>

#define F_    65536
#define LP_   8
#define NL_   8192
#define DG_   64
#define D_    32
#define ITERS_ 8

typedef float f32x2 __attribute__((ext_vector_type(2)));

// ---------------- helpers ----------------
__device__ __forceinline__ float sigmoidf_(float x) { return 1.0f / (1.0f + __expf(-x)); }
__device__ __forceinline__ float tanhf_(float x)    { return 1.0f - 2.0f / (__expf(2.0f * x) + 1.0f); }
__device__ __forceinline__ float seluf_(float x) {
    const float a = 1.6732632423543772f, s = 1.0507009873554805f;
    return x > 0.0f ? s * x : s * a * (__expf(x) - 1.0f);
}
__device__ __forceinline__ float softplusf_(float x) { return x > 20.0f ? x : log1pf(__expf(x)); }

#define REP32(M) M(0)M(1)M(2)M(3)M(4)M(5)M(6)M(7)M(8)M(9)M(10)M(11)M(12)M(13)M(14)M(15) \
                 M(16)M(17)M(18)M(19)M(20)M(21)M(22)M(23)M(24)M(25)M(26)M(27)M(28)M(29)M(30)M(31)
#define REP16(M) M(0)M(1)M(2)M(3)M(4)M(5)M(6)M(7)M(8)M(9)M(10)M(11)M(12)M(13)M(14)M(15)

// broadcast lane i's value within each 32-lane group (1 LDS-pipe instr); i must be a literal
#define BC32(src, i) __int_as_float(__builtin_amdgcn_ds_swizzle(__float_as_int(src), ((i) << 5)))

// packed fma, scalar weight broadcast from lo/hi half of the pair b:
// lo: d.x += a.x*b.x ; d.y += a.y*b.x
__device__ __forceinline__ void pkfma_lo(f32x2& d, f32x2 a, f32x2 b) {
    asm("v_pk_fma_f32 %0, %1, %2, %0 op_sel:[0,0,0] op_sel_hi:[1,0,1]"
        : "+v"(d) : "v"(a), "v"(b));
}
// hi: d.x += a.x*b.y ; d.y += a.y*b.y
__device__ __forceinline__ void pkfma_hi(f32x2& d, f32x2 a, f32x2 b) {
    asm("v_pk_fma_f32 %0, %1, %2, %0 op_sel:[0,1,0] op_sel_hi:[1,1,1]"
        : "+v"(d) : "v"(a), "v"(b));
}

// ---------------- init: path_state -> pss[:,8,:] ----------------
__global__ __launch_bounds__(256) void k_init_path(
    const float* __restrict__ tr, const float* __restrict__ len,
    const float* __restrict__ loss, const float* __restrict__ prop,
    const float* __restrict__ fe_w1, const float* __restrict__ fe_b1,
    const float* __restrict__ fe_w2, const float* __restrict__ fe_b2,
    float* __restrict__ pss)
{
    const int j = threadIdx.x & 31;
    const int half = (threadIdx.x >> 5) & 1;
    float w2c[32];
#pragma unroll
    for (int i = 0; i < 32; i++) w2c[i] = fe_w2[i * 32 + j];
    const float w10 = fe_w1[j], w11 = fe_w1[32 + j], w12 = fe_w1[64 + j], w13 = fe_w1[96 + j];
    const float b1 = fe_b1[j], b2 = fe_b2[j];
    const int wave = (blockIdx.x * blockDim.x + threadIdx.x) >> 6;
    const int nw = (gridDim.x * blockDim.x) >> 6;
    for (int fp = wave; fp < F_ / 2; fp += nw) {
        const int f = fp * 2 + half;
        float p0 = (tr[f]   - 0.5f) * 2.0f;
        float p1 = (len[f]  - 0.5f) * 2.0f;
        float p2 = (loss[f] - 0.1f) * 5.0f;
        float p3 = (prop[f] - 0.2f) * 3.0f;
        float h1 = seluf_(fmaf(p0, w10, fmaf(p1, w11, fmaf(p2, w12, fmaf(p3, w13, b1)))));
        float acc = b2;
#define ISTEP(i) { float hv = BC32(h1, i); acc = fmaf(hv, w2c[i], acc); }
        REP32(ISTEP)
#undef ISTEP
        pss[(size_t)f * 288 + 8 * 32 + j] = seluf_(acc);
    }
}

// ---------------- init: link load + link_state ----------------
__global__ __launch_bounds__(256) void k_init_link(
    const float* __restrict__ tr, const float* __restrict__ cap, const int* __restrict__ f2lf,
    const float* __restrict__ le_w1, const float* __restrict__ le_b1,
    const float* __restrict__ le_w2, const float* __restrict__ le_b2,
    float* __restrict__ link_state)
{
    const int lane = threadIdx.x & 63;
    const int j = lane & 31;
    float w2c[32];
#pragma unroll
    for (int i = 0; i < 32; i++) w2c[i] = le_w2[i * 32 + j];
    const float w10 = le_w1[j], w11 = le_w1[32 + j];
    const float b1 = le_b1[j], b2 = le_b2[j];
    const int wave = (blockIdx.x * blockDim.x + threadIdx.x) >> 6;
    const int nw = (gridDim.x * blockDim.x) >> 6;
    for (int l = wave; l < NL_; l += nw) {
        int fidx = f2lf[l * 64 + lane];
        float s = tr[fidx];
        s += __shfl_xor(s, 1);  s += __shfl_xor(s, 2);  s += __shfl_xor(s, 4);
        s += __shfl_xor(s, 8);  s += __shfl_xor(s, 16); s += __shfl_xor(s, 32);
        float c = cap[l];
        float load = s * (1.0f / 64.0f) / c;
        float lf0 = (c - 1.0f);
        float h1 = seluf_(fmaf(lf0, w10, fmaf(load, w11, b1)));
        float acc = b2;
#define LSTEP(i) { float hv = BC32(h1, i); acc = fmaf(hv, w2c[i], acc); }
        REP32(LSTEP)
#undef LSTEP
        if (lane < 32) link_state[l * 32 + j] = seluf_(acc);
    }
}

// ---------------- initial mx_link = link_state @ pg_w + pg_b[0] ----------------
__global__ __launch_bounds__(256) void k_mx_link(
    const float* __restrict__ link_state, const float* __restrict__ pg_w,
    const float* __restrict__ pg_b, float* __restrict__ mx_link)
{
    const int j = threadIdx.x & 31;
    const int half = (threadIdx.x >> 5) & 1;
    float wz[32], wr[32], wh[32];
#pragma unroll
    for (int i = 0; i < 32; i++) {
        wz[i] = pg_w[i * 96 + j];
        wr[i] = pg_w[i * 96 + 32 + j];
        wh[i] = pg_w[i * 96 + 64 + j];
    }
    const float b0z = pg_b[j], b0r = pg_b[32 + j], b0h = pg_b[64 + j];
    const int wave = (blockIdx.x * blockDim.x + threadIdx.x) >> 6;
    const int nw = (gridDim.x * blockDim.x) >> 6;
    for (int lp = wave; lp < NL_ / 2; lp += nw) {
        const int l = lp * 2 + half;
        float ls = link_state[l * 32 + j];
        float az = b0z, ar = b0r, ah = b0h;
#define MSTEP(i) { float lv = BC32(ls, i); az = fmaf(lv, wz[i], az); ar = fmaf(lv, wr[i], ar); ah = fmaf(lv, wh[i], ah); }
        REP32(MSTEP)
#undef MSTEP
        float* mp = mx_link + l * 96;
        mp[j] = az; mp[32 + j] = ar; mp[64 + j] = ah;
    }
}

// ---------------- per-iter: path GRU, 2 flows per lane (packed fp32) ----------------
__global__ __launch_bounds__(256, 3) void k_path(
    const float* __restrict__ mx_link, const float* __restrict__ pg_u,
    const float* __restrict__ pg_b, const int* __restrict__ l2f,
    float* __restrict__ pss)
{
    const int j = threadIdx.x & 31;
    const int half = (threadIdx.x >> 5) & 1;   // lane-half handles flow pair (4q+2*half, +1)
    // weights packed over i: up[k] = (u[2k][..j], u[2k+1][..j])
    f32x2 up[48];
#pragma unroll
    for (int k = 0; k < 16; k++) {
        up[k]      = f32x2{pg_u[(2 * k) * 96 + j],      pg_u[(2 * k + 1) * 96 + j]};
        up[16 + k] = f32x2{pg_u[(2 * k) * 96 + 32 + j], pg_u[(2 * k + 1) * 96 + 32 + j]};
        up[32 + k] = f32x2{pg_u[(2 * k) * 96 + 64 + j], pg_u[(2 * k + 1) * 96 + 64 + j]};
    }
    const float b1z = pg_b[96 + j], b1r = pg_b[96 + 32 + j], b1h = pg_b[96 + 64 + j];
    const int wave = (blockIdx.x * blockDim.x + threadIdx.x) >> 6;
    const int nw = (gridDim.x * blockDim.x) >> 6;
    for (int q = wave; q < F_ / 4; q += nw) {
        const int fx = q * 4 + half * 2;
        float* prow0 = pss + (size_t)fx * 288;
        float* prow1 = prow0 + 288;
        const int* lr = l2f + fx * 8;
        int lka[8], lkb[8];
#pragma unroll
        for (int t = 0; t < 8; t++) { lka[t] = lr[t]; lkb[t] = lr[8 + t]; }
        f32x2 hc { prow0[256 + j], prow1[256 + j] };
        prow0[j] = hc.x;
        prow1[j] = hc.y;
#pragma unroll
        for (int t = 0; t < 8; t++) {
            const float* ma = mx_link + lka[t] * 96;
            const float* mb = mx_link + lkb[t] * 96;
            f32x2 az { b1z, b1z }, ar { b1r, b1r }, ah { b1h, b1h };
#define KSTEP(k) { \
            f32x2 h0 { BC32(hc.x, 2 * (k)),     BC32(hc.y, 2 * (k)) }; \
            f32x2 h1 { BC32(hc.x, 2 * (k) + 1), BC32(hc.y, 2 * (k) + 1) }; \
            pkfma_lo(az, h0, up[k]);      pkfma_hi(az, h1, up[k]); \
            pkfma_lo(ar, h0, up[16 + k]); pkfma_hi(ar, h1, up[16 + k]); \
            pkfma_lo(ah, h0, up[32 + k]); pkfma_hi(ah, h1, up[32 + k]); }
            REP16(KSTEP)
#undef KSTEP
            float mzx = ma[j],      mzy = mb[j];
            float mrx = ma[32 + j], mry = mb[32 + j];
            float mhx = ma[64 + j], mhy = mb[64 + j];
            float zx = sigmoidf_(mzx + az.x), zy = sigmoidf_(mzy + az.y);
            float rx = sigmoidf_(mrx + ar.x), ry = sigmoidf_(mry + ar.y);
            float cx = tanhf_(mhx + rx * ah.x), cy = tanhf_(mhy + ry * ah.y);
            hc.x = fmaf(zx, hc.x, (1.0f - zx) * cx);
            hc.y = fmaf(zy, hc.y, (1.0f - zy) * cy);
            prow0[(t + 1) * 32 + j] = hc.x;
            prow1[(t + 1) * 32 + j] = hc.y;
        }
    }
}

// ---------------- per-iter: attention + aggregate + link GRU + next mx_link ----------------
__global__ __launch_bounds__(256) void k_att_fused(
    const float* __restrict__ pss, const int* __restrict__ f2lf, const int* __restrict__ f2lp,
    const float* __restrict__ att_w, const float* __restrict__ att_b,
    const float* __restrict__ lg_w, const float* __restrict__ lg_u, const float* __restrict__ lg_b,
    const float* __restrict__ pg_w, const float* __restrict__ pg_b,
    float* __restrict__ link_state, float* __restrict__ mx_link)
{
    __shared__ float red[4][64][33];
    const int w = threadIdx.x >> 6;
    const int lane = threadIdx.x & 63;
    const int l = blockIdx.x * 4 + w;  // one link per wave
    const int fi = f2lf[l * 64 + lane];
    const int pi = f2lp[l * 64 + lane];
    const float* row = pss + ((size_t)fi * 9 + pi) * 32;
    float pg[32];
#pragma unroll
    for (int i = 0; i < 8; i++) {
        float4 v = ((const float4*)row)[i];
        pg[4 * i] = v.x; pg[4 * i + 1] = v.y; pg[4 * i + 2] = v.z; pg[4 * i + 3] = v.w;
    }
    float a[32];
#pragma unroll
    for (int jj = 0; jj < 32; jj++) {
        float acc = att_b[jj];
#pragma unroll
        for (int i = 0; i < 32; i++) acc = fmaf(pg[i], att_w[i * 32 + jj], acc);
        a[jj] = acc > 0.0f ? acc : 0.2f * acc;   // leaky_relu 0.2
    }
    float m = a[0];
#pragma unroll
    for (int jj = 1; jj < 32; jj++) m = fmaxf(m, a[jj]);
    float ssum = 0.0f;
#pragma unroll
    for (int jj = 0; jj < 32; jj++) { a[jj] = __expf(a[jj] - m); ssum += a[jj]; }
    float inv = 1.0f / ssum;
    float* myrow = &red[w][lane][0];
#pragma unroll
    for (int jj = 0; jj < 32; jj++) myrow[jj] = a[jj] * inv * pg[jj];
    __syncthreads();
    const int j = lane & 31, hh = lane >> 5;
    float s = 0.0f;
#pragma unroll
    for (int d = 0; d < 32; d++) s += red[w][hh * 32 + d][j];
    s += __shfl_xor(s, 32);
    // lanes 0-31: link GRU (in-register, this wave owns link l) + mx for next iter
    if (lane < 32) {
        float x = s;                               // agg[j]
        float h = link_state[l * 32 + j];
        float bz = lg_b[j], br = lg_b[32 + j], bh = lg_b[64 + j];
        float az = lg_b[96 + j], arr = lg_b[96 + 32 + j], ahh = lg_b[96 + 64 + j];
#define ASTEP(i) { \
        float xv = BC32(x, i); \
        float hv = BC32(h, i); \
        bz  = fmaf(xv, lg_w[(i) * 96 + j], bz); \
        br  = fmaf(xv, lg_w[(i) * 96 + 32 + j], br); \
        bh  = fmaf(xv, lg_w[(i) * 96 + 64 + j], bh); \
        az  = fmaf(hv, lg_u[(i) * 96 + j], az); \
        arr = fmaf(hv, lg_u[(i) * 96 + 32 + j], arr); \
        ahh = fmaf(hv, lg_u[(i) * 96 + 64 + j], ahh); }
        REP32(ASTEP)
#undef ASTEP
        float z = sigmoidf_(bz + az);
        float r = sigmoidf_(br + arr);
        float c = tanhf_(bh + r * ahh);
        float hn = fmaf(z, h, (1.0f - z) * c);
        link_state[l * 32 + j] = hn;
        // mx_link[l] = hn @ pg_w + pg_b[0]  (for next iteration's k_path)
        float mz = pg_b[j], mr = pg_b[32 + j], mh = pg_b[64 + j];
#define MXSTEP(i) { \
        float hv = BC32(hn, i); \
        mz = fmaf(hv, pg_w[(i) * 96 + j], mz); \
        mr = fmaf(hv, pg_w[(i) * 96 + 32 + j], mr); \
        mh = fmaf(hv, pg_w[(i) * 96 + 64 + j], mh); }
        REP32(MXSTEP)
#undef MXSTEP
        float* mp = mx_link + l * 96;
        mp[j] = mz; mp[32 + j] = mr; mp[64 + j] = mh;
    }
}

// ---------------- readout ----------------
__global__ __launch_bounds__(256) void k_readout(
    const float* __restrict__ pss, const int* __restrict__ l2f,
    const float* __restrict__ cap, const float* __restrict__ prop,
    const float* __restrict__ ro_w1, const float* __restrict__ b1,
    const float* __restrict__ ro_w2, const float* __restrict__ b2,
    const float* __restrict__ w3, const float* __restrict__ b3,
    float* __restrict__ out)
{
    const int tid = blockIdx.x * blockDim.x + threadIdx.x;  // F*8 total
    const int f = tid >> 3, t = tid & 7;
    const float* row = pss + ((size_t)f * 9 + 1 + t) * 32;
    float xr[32];
#pragma unroll
    for (int i = 0; i < 8; i++) {
        float4 v = ((const float4*)row)[i];
        xr[4 * i] = v.x; xr[4 * i + 1] = v.y; xr[4 * i + 2] = v.z; xr[4 * i + 3] = v.w;
    }
    float h1[16];
#pragma unroll
    for (int jj = 0; jj < 16; jj++) {
        float acc = b1[jj];
#pragma unroll
        for (int i = 0; i < 32; i++) acc = fmaf(xr[i], ro_w1[i * 16 + jj], acc);
        h1[jj] = seluf_(acc);
    }
    float h2[8];
#pragma unroll
    for (int jj = 0; jj < 8; jj++) {
        float acc = b2[jj];
#pragma unroll
        for (int i = 0; i < 16; i++) acc = fmaf(h1[i], ro_w2[i * 8 + jj], acc);
        h2[jj] = seluf_(acc);
    }
    float o = b3[0];
#pragma unroll
    for (int i = 0; i < 8; i++) o = fmaf(h2[i], w3[i], o);
    o = softplusf_(o);
    int link = l2f[f * 8 + t];
    float v = o / cap[link];
    v += __shfl_xor(v, 1, 8);
    v += __shfl_xor(v, 2, 8);
    v += __shfl_xor(v, 4, 8);
    if (t == 0) out[f] = v + prop[f];
}

// ---------------- host ----------------
extern "C" void kernel_launch(void* const* d_in, const int* in_sizes, int n_in,
                              void* d_out, int out_size, void* d_ws, size_t ws_size,
                              hipStream_t stream) {
    const float* flow_traffic = (const float*)d_in[0];
    const float* flow_length  = (const float*)d_in[1];
    const float* flow_loss    = (const float*)d_in[2];
    const float* flow_prop    = (const float*)d_in[3];
    const float* link_cap     = (const float*)d_in[5];
    const int*   l2f          = (const int*)d_in[6];
    const int*   f2lf         = (const int*)d_in[7];
    const int*   f2lp         = (const int*)d_in[8];
    const float* fe_w1 = (const float*)d_in[9],  *fe_b1 = (const float*)d_in[10];
    const float* fe_w2 = (const float*)d_in[11], *fe_b2 = (const float*)d_in[12];
    const float* le_w1 = (const float*)d_in[13], *le_b1 = (const float*)d_in[14];
    const float* le_w2 = (const float*)d_in[15], *le_b2 = (const float*)d_in[16];
    const float* att_w = (const float*)d_in[17], *att_b = (const float*)d_in[18];
    const float* pg_w  = (const float*)d_in[19], *pg_u  = (const float*)d_in[20], *pg_b = (const float*)d_in[21];
    const float* lg_w  = (const float*)d_in[22], *lg_u  = (const float*)d_in[23], *lg_b = (const float*)d_in[24];
    const float* ro_w1 = (const float*)d_in[25], *ro_b1 = (const float*)d_in[26];
    const float* ro_w2 = (const float*)d_in[27], *ro_b2 = (const float*)d_in[28];
    const float* ro_w3 = (const float*)d_in[29], *ro_b3 = (const float*)d_in[30];
    float* out = (float*)d_out;

    float* ws = (float*)d_ws;
    float* pss        = ws;                                   // F*9*32
    float* link_state = pss + (size_t)F_ * 288;               // NL*32
    float* mx_link    = link_state + NL_ * 32;                // NL*96

    k_init_path<<<512, 256, 0, stream>>>(flow_traffic, flow_length, flow_loss, flow_prop,
                                         fe_w1, fe_b1, fe_w2, fe_b2, pss);
    k_init_link<<<512, 256, 0, stream>>>(flow_traffic, link_cap, f2lf,
                                         le_w1, le_b1, le_w2, le_b2, link_state);
    k_mx_link<<<64, 256, 0, stream>>>(link_state, pg_w, pg_b, mx_link);
    for (int it = 0; it < ITERS_; ++it) {
        k_path<<<2048, 256, 0, stream>>>(mx_link, pg_u, pg_b, l2f, pss);
        k_att_fused<<<NL_ / 4, 256, 0, stream>>>(pss, f2lf, f2lp, att_w, att_b,
                                                 lg_w, lg_u, lg_b, pg_w, pg_b,
                                                 link_state, mx_link);
    }
    k_readout<<<F_ * 8 / 256, 256, 0, stream>>>(pss, l2f, link_cap, flow_prop,
                                                ro_w1, ro_b1, ro_w2, ro_b2, ro_w3, ro_b3, out);
}

// Round 4
// 652.383 us; speedup vs baseline: 2.0707x; 1.6612x over previous
//
#include <hip/hip_runtime.h>
#include <hip/hip_bf16.h>
#include <cstddef>

#define F_    65536
#define LP_   8
#define NL_   8192
#define DG_   64
#define D_    32
#define ITERS_ 8

typedef short bf16x8 __attribute__((ext_vector_type(8)));
typedef float f32x4 __attribute__((ext_vector_type(4)));
typedef unsigned int u32x4 __attribute__((ext_vector_type(4)));

// ---------------- helpers ----------------
__device__ __forceinline__ float sigmoidf_(float x) { return 1.0f / (1.0f + __expf(-x)); }
__device__ __forceinline__ float tanhf_(float x)    { return 1.0f - 2.0f / (__expf(2.0f * x) + 1.0f); }
__device__ __forceinline__ float seluf_(float x) {
    const float a = 1.6732632423543772f, s = 1.0507009873554805f;
    return x > 0.0f ? s * x : s * a * (__expf(x) - 1.0f);
}
__device__ __forceinline__ float softplusf_(float x) { return x > 20.0f ? x : log1pf(__expf(x)); }

#define REP32(M) M(0)M(1)M(2)M(3)M(4)M(5)M(6)M(7)M(8)M(9)M(10)M(11)M(12)M(13)M(14)M(15) \
                 M(16)M(17)M(18)M(19)M(20)M(21)M(22)M(23)M(24)M(25)M(26)M(27)M(28)M(29)M(30)M(31)

// broadcast lane i's value within each 32-lane group (1 LDS-pipe instr); i must be a literal
#define BC32(src, i) __int_as_float(__builtin_amdgcn_ds_swizzle(__float_as_int(src), ((i) << 5)))

// packed f32->bf16 (RNE): r[15:0]=bf16(a), r[31:16]=bf16(b)
__device__ __forceinline__ unsigned int cvtpk_bf16(float a, float b) {
    unsigned int r;
    asm("v_cvt_pk_bf16_f32 %0, %1, %2" : "=v"(r) : "v"(a), "v"(b));
    return r;
}

// split 8 f32 into hi/lo bf16 fragments (hi + lo ~= exact f32)
__device__ __forceinline__ void mk_frag(float4 v0, float4 v1, bf16x8& hi, bf16x8& lo) {
    u32x4 uh;
    uh.x = cvtpk_bf16(v0.x, v0.y);
    uh.y = cvtpk_bf16(v0.z, v0.w);
    uh.z = cvtpk_bf16(v1.x, v1.y);
    uh.w = cvtpk_bf16(v1.z, v1.w);
    float r0 = __uint_as_float(uh.x << 16);
    float r1 = __uint_as_float(uh.x & 0xFFFF0000u);
    float r2 = __uint_as_float(uh.y << 16);
    float r3 = __uint_as_float(uh.y & 0xFFFF0000u);
    float r4 = __uint_as_float(uh.z << 16);
    float r5 = __uint_as_float(uh.z & 0xFFFF0000u);
    float r6 = __uint_as_float(uh.w << 16);
    float r7 = __uint_as_float(uh.w & 0xFFFF0000u);
    u32x4 ul;
    ul.x = cvtpk_bf16(v0.x - r0, v0.y - r1);
    ul.y = cvtpk_bf16(v0.z - r2, v0.w - r3);
    ul.z = cvtpk_bf16(v1.x - r4, v1.y - r5);
    ul.w = cvtpk_bf16(v1.z - r6, v1.w - r7);
    hi = __builtin_bit_cast(bf16x8, uh);
    lo = __builtin_bit_cast(bf16x8, ul);
}

// ---------------- init: path_state -> pss[:,8,:] ----------------
__global__ __launch_bounds__(256) void k_init_path(
    const float* __restrict__ tr, const float* __restrict__ len,
    const float* __restrict__ loss, const float* __restrict__ prop,
    const float* __restrict__ fe_w1, const float* __restrict__ fe_b1,
    const float* __restrict__ fe_w2, const float* __restrict__ fe_b2,
    float* __restrict__ pss)
{
    const int j = threadIdx.x & 31;
    const int half = (threadIdx.x >> 5) & 1;
    float w2c[32];
#pragma unroll
    for (int i = 0; i < 32; i++) w2c[i] = fe_w2[i * 32 + j];
    const float w10 = fe_w1[j], w11 = fe_w1[32 + j], w12 = fe_w1[64 + j], w13 = fe_w1[96 + j];
    const float b1 = fe_b1[j], b2 = fe_b2[j];
    const int wave = (blockIdx.x * blockDim.x + threadIdx.x) >> 6;
    const int nw = (gridDim.x * blockDim.x) >> 6;
    for (int fp = wave; fp < F_ / 2; fp += nw) {
        const int f = fp * 2 + half;
        float p0 = (tr[f]   - 0.5f) * 2.0f;
        float p1 = (len[f]  - 0.5f) * 2.0f;
        float p2 = (loss[f] - 0.1f) * 5.0f;
        float p3 = (prop[f] - 0.2f) * 3.0f;
        float h1 = seluf_(fmaf(p0, w10, fmaf(p1, w11, fmaf(p2, w12, fmaf(p3, w13, b1)))));
        float acc = b2;
#define ISTEP(i) { float hv = BC32(h1, i); acc = fmaf(hv, w2c[i], acc); }
        REP32(ISTEP)
#undef ISTEP
        pss[(size_t)f * 288 + 8 * 32 + j] = seluf_(acc);
    }
}

// ---------------- init: link load + link_state ----------------
__global__ __launch_bounds__(256) void k_init_link(
    const float* __restrict__ tr, const float* __restrict__ cap, const int* __restrict__ f2lf,
    const float* __restrict__ le_w1, const float* __restrict__ le_b1,
    const float* __restrict__ le_w2, const float* __restrict__ le_b2,
    float* __restrict__ link_state)
{
    const int lane = threadIdx.x & 63;
    const int j = lane & 31;
    float w2c[32];
#pragma unroll
    for (int i = 0; i < 32; i++) w2c[i] = le_w2[i * 32 + j];
    const float w10 = le_w1[j], w11 = le_w1[32 + j];
    const float b1 = le_b1[j], b2 = le_b2[j];
    const int wave = (blockIdx.x * blockDim.x + threadIdx.x) >> 6;
    const int nw = (gridDim.x * blockDim.x) >> 6;
    for (int l = wave; l < NL_; l += nw) {
        int fidx = f2lf[l * 64 + lane];
        float s = tr[fidx];
        s += __shfl_xor(s, 1);  s += __shfl_xor(s, 2);  s += __shfl_xor(s, 4);
        s += __shfl_xor(s, 8);  s += __shfl_xor(s, 16); s += __shfl_xor(s, 32);
        float c = cap[l];
        float load = s * (1.0f / 64.0f) / c;
        float lf0 = (c - 1.0f);
        float h1 = seluf_(fmaf(lf0, w10, fmaf(load, w11, b1)));
        float acc = b2;
#define LSTEP(i) { float hv = BC32(h1, i); acc = fmaf(hv, w2c[i], acc); }
        REP32(LSTEP)
#undef LSTEP
        if (lane < 32) link_state[l * 32 + j] = seluf_(acc);
    }
}

// ---------------- initial mx_link = link_state @ pg_w + pg_b[0] ----------------
__global__ __launch_bounds__(256) void k_mx_link(
    const float* __restrict__ link_state, const float* __restrict__ pg_w,
    const float* __restrict__ pg_b, float* __restrict__ mx_link)
{
    const int j = threadIdx.x & 31;
    const int half = (threadIdx.x >> 5) & 1;
    float wz[32], wr[32], wh[32];
#pragma unroll
    for (int i = 0; i < 32; i++) {
        wz[i] = pg_w[i * 96 + j];
        wr[i] = pg_w[i * 96 + 32 + j];
        wh[i] = pg_w[i * 96 + 64 + j];
    }
    const float b0z = pg_b[j], b0r = pg_b[32 + j], b0h = pg_b[64 + j];
    const int wave = (blockIdx.x * blockDim.x + threadIdx.x) >> 6;
    const int nw = (gridDim.x * blockDim.x) >> 6;
    for (int lp = wave; lp < NL_ / 2; lp += nw) {
        const int l = lp * 2 + half;
        float ls = link_state[l * 32 + j];
        float az = b0z, ar = b0r, ah = b0h;
#define MSTEP(i) { float lv = BC32(ls, i); az = fmaf(lv, wz[i], az); ar = fmaf(lv, wr[i], ar); ah = fmaf(lv, wh[i], ah); }
        REP32(MSTEP)
#undef MSTEP
        float* mp = mx_link + l * 96;
        mp[j] = az; mp[32 + j] = ar; mp[64 + j] = ah;
    }
}

// ---------------- per-iter: path GRU via MFMA, 16 flows per wave ----------------
// H(16x32) @ U(32x96) as 6 mfma_f32_16x16x32_bf16 tiles, hi/lo split on both
// operands (3 cross terms) for ~fp32 accuracy. C layout: col=lane&15,
// row=(lane>>4)*4+reg. LDS 16x32 transpose (stride 36: conflict-free b128)
// produces coalesced pss stores + next-step A-fragment.
__global__ __launch_bounds__(256, 3) void k_path(
    const float* __restrict__ mx_link, const float* __restrict__ pg_u,
    const float* __restrict__ pg_b, const int* __restrict__ l2f,
    float* __restrict__ pss)
{
    __shared__ __align__(16) float xlds[4][576];
    const int lane = threadIdx.x & 63;
    const int wid = threadIdx.x >> 6;
    const int jj = lane & 15;       // tile col / transposed-read flow
    const int g4 = lane >> 4;       // 0..3
    const int task = (blockIdx.x * blockDim.x + threadIdx.x) >> 6;   // 0..4095
    const int fb = task * 16;

    // B fragments (U) hi/lo: tile tl covers cols [tl*16, tl*16+16); lane holds
    // k = g4*8+e, n = jj.
    bf16x8 bhi[6], blo[6];
#pragma unroll
    for (int tl = 0; tl < 6; tl++) {
        const float* up = pg_u + (g4 * 8) * 96 + tl * 16 + jj;
        float4 v0 = make_float4(up[0],   up[96],  up[192], up[288]);
        float4 v1 = make_float4(up[384], up[480], up[576], up[672]);
        mk_frag(v0, v1, bhi[tl], blo[tl]);
    }
    // recurrent biases for this lane's cols: [gate g][half hf]
    float b1v[6];
#pragma unroll
    for (int g = 0; g < 3; g++) {
#pragma unroll
        for (int hf = 0; hf < 2; hf++)
            b1v[g * 2 + hf] = pg_b[96 + g * 32 + hf * 16 + jj];
    }
    // init A fragment from pss slot 8 (flow fb+jj, dims g4*8..+7); copy to slot 0
    float* pbase = pss + (size_t)(fb + jj) * 288;
    float4 v0 = *(const float4*)(pbase + 256 + g4 * 8);
    float4 v1 = *(const float4*)(pbase + 256 + g4 * 8 + 4);
    *(float4*)(pbase + g4 * 8)     = v0;
    *(float4*)(pbase + g4 * 8 + 4) = v1;
    bf16x8 ahi, alo;
    mk_frag(v0, v1, ahi, alo);
    // h in C layout: flows 4*g4+r, cols {jj, jj+16}
    float hC[4][2];
#pragma unroll
    for (int r = 0; r < 4; r++) {
        const float* hp = pss + (size_t)(fb + 4 * g4 + r) * 288 + 256;
        hC[r][0] = hp[jj];
        hC[r][1] = hp[jj + 16];
    }
    float* wl = &xlds[wid][0];

#pragma unroll
    for (int t = 0; t < 8; t++) {
        // gather mx for this step's links (group-uniform link per flow)
        float mxv[3][4][2];
#pragma unroll
        for (int r = 0; r < 4; r++) {
            int lk = l2f[(fb + 4 * g4 + r) * 8 + t];
            const float* mp = mx_link + lk * 96;
#pragma unroll
            for (int g = 0; g < 3; g++) {
                mxv[g][r][0] = mp[g * 32 + jj];
                mxv[g][r][1] = mp[g * 32 + jj + 16];
            }
        }
        // mh = H @ U  (hi*hi + hi*lo + lo*hi)
        f32x4 acc[6];
#pragma unroll
        for (int tl = 0; tl < 6; tl++) {
            acc[tl] = f32x4{0.0f, 0.0f, 0.0f, 0.0f};
            acc[tl] = __builtin_amdgcn_mfma_f32_16x16x32_bf16(ahi, bhi[tl], acc[tl], 0, 0, 0);
            acc[tl] = __builtin_amdgcn_mfma_f32_16x16x32_bf16(ahi, blo[tl], acc[tl], 0, 0, 0);
            acc[tl] = __builtin_amdgcn_mfma_f32_16x16x32_bf16(alo, bhi[tl], acc[tl], 0, 0, 0);
        }
        // gates + state update in C layout; stage h_new into LDS for transpose
#pragma unroll
        for (int r = 0; r < 4; r++) {
#pragma unroll
            for (int hf = 0; hf < 2; hf++) {
                float z  = sigmoidf_(mxv[0][r][hf] + acc[0 + hf][r] + b1v[0 + hf]);
                float rg = sigmoidf_(mxv[1][r][hf] + acc[2 + hf][r] + b1v[2 + hf]);
                float c  = tanhf_(mxv[2][r][hf] + rg * (acc[4 + hf][r] + b1v[4 + hf]));
                float hn = fmaf(z, hC[r][hf], (1.0f - z) * c);
                hC[r][hf] = hn;
                wl[(4 * g4 + r) * 36 + jj + hf * 16] = hn;
            }
        }
        // transposed read (lane -> flow jj, dims g4*8..+7): coalesced store + next A
        float4 n0 = *(const float4*)&wl[jj * 36 + g4 * 8];
        float4 n1 = *(const float4*)&wl[jj * 36 + g4 * 8 + 4];
        *(float4*)(pbase + (t + 1) * 32 + g4 * 8)     = n0;
        *(float4*)(pbase + (t + 1) * 32 + g4 * 8 + 4) = n1;
        if (t < 7) mk_frag(n0, n1, ahi, alo);
    }
}

// ---------------- per-iter: attention + aggregate + link GRU + next mx_link ----------------
__global__ __launch_bounds__(256) void k_att_fused(
    const float* __restrict__ pss, const int* __restrict__ f2lf, const int* __restrict__ f2lp,
    const float* __restrict__ att_w, const float* __restrict__ att_b,
    const float* __restrict__ lg_w, const float* __restrict__ lg_u, const float* __restrict__ lg_b,
    const float* __restrict__ pg_w, const float* __restrict__ pg_b,
    float* __restrict__ link_state, float* __restrict__ mx_link)
{
    __shared__ float red[4][64][33];
    const int w = threadIdx.x >> 6;
    const int lane = threadIdx.x & 63;
    const int l = blockIdx.x * 4 + w;  // one link per wave
    const int fi = f2lf[l * 64 + lane];
    const int pi = f2lp[l * 64 + lane];
    const float* row = pss + ((size_t)fi * 9 + pi) * 32;
    float pg[32];
#pragma unroll
    for (int i = 0; i < 8; i++) {
        float4 v = ((const float4*)row)[i];
        pg[4 * i] = v.x; pg[4 * i + 1] = v.y; pg[4 * i + 2] = v.z; pg[4 * i + 3] = v.w;
    }
    float a[32];
#pragma unroll
    for (int jj = 0; jj < 32; jj++) {
        float acc = att_b[jj];
#pragma unroll
        for (int i = 0; i < 32; i++) acc = fmaf(pg[i], att_w[i * 32 + jj], acc);
        a[jj] = acc > 0.0f ? acc : 0.2f * acc;   // leaky_relu 0.2
    }
    float m = a[0];
#pragma unroll
    for (int jj = 1; jj < 32; jj++) m = fmaxf(m, a[jj]);
    float ssum = 0.0f;
#pragma unroll
    for (int jj = 0; jj < 32; jj++) { a[jj] = __expf(a[jj] - m); ssum += a[jj]; }
    float inv = 1.0f / ssum;
    float* myrow = &red[w][lane][0];
#pragma unroll
    for (int jj = 0; jj < 32; jj++) myrow[jj] = a[jj] * inv * pg[jj];
    __syncthreads();
    const int j = lane & 31, hh = lane >> 5;
    float s = 0.0f;
#pragma unroll
    for (int d = 0; d < 32; d++) s += red[w][hh * 32 + d][j];
    s += __shfl_xor(s, 32);    // all 64 lanes now hold agg[j]
    // split GRU matvecs: lanes 0-31 h-side (lg_u), lanes 32-63 x-side (lg_w)
    const float hval = link_state[l * 32 + j];
    float src = (lane < 32) ? hval : s;
    const float* wb = (lane < 32) ? lg_u : lg_w;
    float p0 = (lane < 32) ? lg_b[96 + j]      : lg_b[j];
    float p1 = (lane < 32) ? lg_b[96 + 32 + j] : lg_b[32 + j];
    float p2 = (lane < 32) ? lg_b[96 + 64 + j] : lg_b[64 + j];
#define ASTEP(i) { float v = BC32(src, i); \
    p0 = fmaf(v, wb[(i) * 96 + j], p0); \
    p1 = fmaf(v, wb[(i) * 96 + 32 + j], p1); \
    p2 = fmaf(v, wb[(i) * 96 + 64 + j], p2); }
    REP32(ASTEP)
#undef ASTEP
    float q0 = __shfl_xor(p0, 32);
    float q1 = __shfl_xor(p1, 32);
    float q2 = __shfl_xor(p2, 32);
    float hn = 0.0f;
    if (lane < 32) {
        float z = sigmoidf_(q0 + p0);
        float r = sigmoidf_(q1 + p1);
        float c = tanhf_(q2 + r * p2);
        hn = fmaf(z, hval, (1.0f - z) * c);
        link_state[l * 32 + j] = hn;
    }
    float hnb = __shfl(hn, j);   // broadcast lower-half hn to both halves
    // mx_link[l] = hn @ pg_w + pg_b[0]: lanes 0-31 do mz,mr; lanes 32-63 do mh
    float m0 = (lane < 32) ? pg_b[j]      : pg_b[64 + j];
    float m1 = (lane < 32) ? pg_b[32 + j] : 0.0f;
    const float* c0 = (lane < 32) ? pg_w + j      : pg_w + 64 + j;
    const float* c1 = (lane < 32) ? pg_w + 32 + j : pg_w + 64 + j;
#define MXS(i) { float v = BC32(hnb, i); \
    m0 = fmaf(v, c0[(i) * 96], m0); \
    m1 = fmaf(v, c1[(i) * 96], m1); }
    REP32(MXS)
#undef MXS
    float* mp = mx_link + l * 96;
    if (lane < 32) { mp[j] = m0; mp[32 + j] = m1; }
    else           { mp[64 + j] = m0; }
}

// ---------------- readout ----------------
__global__ __launch_bounds__(256) void k_readout(
    const float* __restrict__ pss, const int* __restrict__ l2f,
    const float* __restrict__ cap, const float* __restrict__ prop,
    const float* __restrict__ ro_w1, const float* __restrict__ b1,
    const float* __restrict__ ro_w2, const float* __restrict__ b2,
    const float* __restrict__ w3, const float* __restrict__ b3,
    float* __restrict__ out)
{
    const int tid = blockIdx.x * blockDim.x + threadIdx.x;  // F*8 total
    const int f = tid >> 3, t = tid & 7;
    const float* row = pss + ((size_t)f * 9 + 1 + t) * 32;
    float xr[32];
#pragma unroll
    for (int i = 0; i < 8; i++) {
        float4 v = ((const float4*)row)[i];
        xr[4 * i] = v.x; xr[4 * i + 1] = v.y; xr[4 * i + 2] = v.z; xr[4 * i + 3] = v.w;
    }
    float h1[16];
#pragma unroll
    for (int jj = 0; jj < 16; jj++) {
        float acc = b1[jj];
#pragma unroll
        for (int i = 0; i < 32; i++) acc = fmaf(xr[i], ro_w1[i * 16 + jj], acc);
        h1[jj] = seluf_(acc);
    }
    float h2[8];
#pragma unroll
    for (int jj = 0; jj < 8; jj++) {
        float acc = b2[jj];
#pragma unroll
        for (int i = 0; i < 16; i++) acc = fmaf(h1[i], ro_w2[i * 8 + jj], acc);
        h2[jj] = seluf_(acc);
    }
    float o = b3[0];
#pragma unroll
    for (int i = 0; i < 8; i++) o = fmaf(h2[i], w3[i], o);
    o = softplusf_(o);
    int link = l2f[f * 8 + t];
    float v = o / cap[link];
    v += __shfl_xor(v, 1, 8);
    v += __shfl_xor(v, 2, 8);
    v += __shfl_xor(v, 4, 8);
    if (t == 0) out[f] = v + prop[f];
}

// ---------------- host ----------------
extern "C" void kernel_launch(void* const* d_in, const int* in_sizes, int n_in,
                              void* d_out, int out_size, void* d_ws, size_t ws_size,
                              hipStream_t stream) {
    const float* flow_traffic = (const float*)d_in[0];
    const float* flow_length  = (const float*)d_in[1];
    const float* flow_loss    = (const float*)d_in[2];
    const float* flow_prop    = (const float*)d_in[3];
    const float* link_cap     = (const float*)d_in[5];
    const int*   l2f          = (const int*)d_in[6];
    const int*   f2lf         = (const int*)d_in[7];
    const int*   f2lp         = (const int*)d_in[8];
    const float* fe_w1 = (const float*)d_in[9],  *fe_b1 = (const float*)d_in[10];
    const float* fe_w2 = (const float*)d_in[11], *fe_b2 = (const float*)d_in[12];
    const float* le_w1 = (const float*)d_in[13], *le_b1 = (const float*)d_in[14];
    const float* le_w2 = (const float*)d_in[15], *le_b2 = (const float*)d_in[16];
    const float* att_w = (const float*)d_in[17], *att_b = (const float*)d_in[18];
    const float* pg_w  = (const float*)d_in[19], *pg_u  = (const float*)d_in[20], *pg_b = (const float*)d_in[21];
    const float* lg_w  = (const float*)d_in[22], *lg_u  = (const float*)d_in[23], *lg_b = (const float*)d_in[24];
    const float* ro_w1 = (const float*)d_in[25], *ro_b1 = (const float*)d_in[26];
    const float* ro_w2 = (const float*)d_in[27], *ro_b2 = (const float*)d_in[28];
    const float* ro_w3 = (const float*)d_in[29], *ro_b3 = (const float*)d_in[30];
    float* out = (float*)d_out;

    float* ws = (float*)d_ws;
    float* pss        = ws;                                   // F*9*32
    float* link_state = pss + (size_t)F_ * 288;               // NL*32
    float* mx_link    = link_state + NL_ * 32;                // NL*96

    k_init_path<<<512, 256, 0, stream>>>(flow_traffic, flow_length, flow_loss, flow_prop,
                                         fe_w1, fe_b1, fe_w2, fe_b2, pss);
    k_init_link<<<512, 256, 0, stream>>>(flow_traffic, link_cap, f2lf,
                                         le_w1, le_b1, le_w2, le_b2, link_state);
    k_mx_link<<<64, 256, 0, stream>>>(link_state, pg_w, pg_b, mx_link);
    for (int it = 0; it < ITERS_; ++it) {
        k_path<<<F_ / 64, 256, 0, stream>>>(mx_link, pg_u, pg_b, l2f, pss);
        k_att_fused<<<NL_ / 4, 256, 0, stream>>>(pss, f2lf, f2lp, att_w, att_b,
                                                 lg_w, lg_u, lg_b, pg_w, pg_b,
                                                 link_state, mx_link);
    }
    k_readout<<<F_ * 8 / 256, 256, 0, stream>>>(pss, l2f, link_cap, flow_prop,
                                                ro_w1, ro_b1, ro_w2, ro_b2, ro_w3, ro_b3, out);
}